// Round 5
// baseline (164.021 us; speedup 1.0000x reference)
//
#include <hip/hip_runtime.h>
#include <math.h>

// GaussianMixture log-likelihood: ll[n] = logsumexp_m( wlog[m] - dx^T G_m dx )
// R10: spatial pruning. R9b falsified the trans theory (removing exp2 changed
// nothing): kernel is at the fp32-VALU roofline for issued work (pk_f32 = same
// FLOP rate as scalar f32; 157.3TF spec = 1 FMA/lane/cyc). Only lever left:
// do less work. Data is a KDE (sigma~1/15, mu in [0,1]^2, x~N(0,1)):
//  - counting-sort samples by 64x64 cell over [-2,2]^2 (3 tiny kernels)
//  - prep cell-sorts components (16x16 over [0,1]^2) + per-chunk bbox meta
//  - gmix: waves get chunks round-robin (spatial coverage -> tight anchor);
//    per-chunk wave-uniform skip test: UB(chunk,wavebbox) < anchor - 32 ->
//    contribution < 2^-21 relative (anchor = achieved max = safe lower bound;
//    skip is unconditionally correct, looseness only costs skip-rate)
//  - block-id odd-mult swizzle spreads heavy central blocks (load balance)
//  - ws too small / ragged M -> falls back to exact current behavior
// Numerics unchanged from R9b (Schraudolph exp2 in hot loop; absmax 4.0 passed).
// Max tree stays COMPLETE (R5 NaN lesson); coefficient loads stay wave-uniform
// (R3 lesson).

#if __has_builtin(__builtin_amdgcn_exp2f)
#define EXP2(x) __builtin_amdgcn_exp2f(x)
#else
#define EXP2(x) exp2f(x)
#endif

typedef float v4f __attribute__((ext_vector_type(4)));
typedef int   i4  __attribute__((ext_vector_type(4)));

#if __has_builtin(__builtin_elementwise_max)
#define V4MAX(a, b) __builtin_elementwise_max(a, b)
#else
static __device__ inline v4f V4MAX(v4f a, v4f b) {
  v4f r; r.x = fmaxf(a.x, b.x); r.y = fmaxf(a.y, b.y);
  r.z = fmaxf(a.z, b.z); r.w = fmaxf(a.w, b.w); return r;
}
#endif

static __device__ __forceinline__ v4f exp2_hw4(v4f d) {
  v4f r; r.x = EXP2(d.x); r.y = EXP2(d.y); r.z = EXP2(d.z); r.w = EXP2(d.w);
  return r;
}

// Schraudolph exp2 (fp32): y = bitcast(int(x*2^23 + 127*2^23 - C)), C=366393
#define SCH_K1   8388608.0f      // 2^23
#define SCH_K2   1064986823.0f   // 127*2^23 - 366393
#define SCH_TMIN 58353856.0f     // SCH_K2 - 120*2^23 (clamp keeps cvt valid)

#define SPLIT 8
#define CH  16    // fast-path chunk
#define CHG 8     // general-path chunk
#define PC  16    // comp cell grid (PCxPC over [0,1]^2)
#define SC  64    // sample cell grid (SCxSC over [-2,2]^2)
#define SCELLS (SC * SC)
#define T_SKIP 32.0f
#define MAXM_SORT 2048

__global__ __launch_bounds__(256) void prep_kernel(
    const float* __restrict__ mu,
    const float* __restrict__ A,
    const float* __restrict__ w,
    float* __restrict__ C,   // [6][M] planes + header + chunk meta
    int M, int psort) {
  __shared__ float red[256];
  __shared__ int uni[256];
  __shared__ int hist[PC * PC];
  __shared__ int off2[PC * PC];
  __shared__ float sMu0[MAXM_SORT];
  __shared__ float sMu1[MAXM_SORT];
  __shared__ float sWl[MAXM_SORT];
  const int t = threadIdx.x;
  const int NC = M / CH;

  float mx = -INFINITY;
  for (int m = t; m < M; m += 256) mx = fmaxf(mx, w[m]);
  red[t] = mx; __syncthreads();
  for (int s = 128; s > 0; s >>= 1) {
    if (t < s) red[t] = fmaxf(red[t], red[t + s]);
    __syncthreads();
  }
  const float wmax = red[0]; __syncthreads();

  float sum = 0.f;
  for (int m = t; m < M; m += 256) sum += expf(w[m] - wmax);
  red[t] = sum; __syncthreads();
  for (int s = 128; s > 0; s >>= 1) {
    if (t < s) red[t] += red[t + s];
    __syncthreads();
  }
  const float logZ = wmax + logf(red[0]);

  const float r00 = A[0], r01 = A[1], r10 = A[2], r11 = A[3];
  const float rg00 = 0.5f * (r00 * r00 + r01 * r01);
  const float rg01 = 0.5f * (r00 * r10 + r01 * r11);
  const float rg11 = 0.5f * (r10 * r10 + r11 * r11);

  // histogram of comp cells
  if (t < PC * PC) hist[t] = 0;
  __syncthreads();
  if (psort) {
    for (int m = t; m < M; m += 256) {
      const float mu0 = mu[m * 2 + 0], mu1 = mu[m * 2 + 1];
      int cx = (int)(mu0 * (float)PC); cx = min(PC - 1, max(0, cx));
      int cy = (int)(mu1 * (float)PC); cy = min(PC - 1, max(0, cy));
      atomicAdd(&hist[cy * PC + cx], 1);
    }
  }
  __syncthreads();
  if (t == 0) {  // exclusive scan
    int acc = 0;
    for (int i = 0; i < PC * PC; ++i) { int c = hist[i]; off2[i] = acc; acc += c; }
  }
  __syncthreads();

  const float LOG2E = 1.44269504088896340736f;
  int myuni = 1;
  for (int m = t; m < M; m += 256) {
    const float a00 = A[m * 4 + 0], a01 = A[m * 4 + 1];
    const float a10 = A[m * 4 + 2], a11 = A[m * 4 + 3];
    const float g00 = 0.5f * (a00 * a00 + a01 * a01);
    const float g01 = 0.5f * (a00 * a10 + a01 * a11);
    const float g11 = 0.5f * (a10 * a10 + a11 * a11);
    const float g01s = 2.0f * g01;
    const float det = g00 * g11 - g01 * g01;
    const float wlog = (w[m] - logZ) + 0.5f * logf(det);
    const float mu0 = mu[m * 2 + 0], mu1 = mu[m * 2 + 1];
    const float c0 = wlog - (g00 * mu0 * mu0 + g01s * mu0 * mu1 + g11 * mu1 * mu1);
    const float c2 = 2.0f * g00 * mu0 + g01s * mu1;
    const float c4 = 2.0f * g11 * mu1 + g01s * mu0;
    int slot = m;
    if (psort) {
      int cx = (int)(mu0 * (float)PC); cx = min(PC - 1, max(0, cx));
      int cy = (int)(mu1 * (float)PC); cy = min(PC - 1, max(0, cy));
      slot = atomicAdd(&off2[cy * PC + cx], 1);
      sMu0[slot] = mu0; sMu1[slot] = mu1; sWl[slot] = LOG2E * wlog;
    }
    C[0 * M + slot] = LOG2E * c0;
    C[1 * M + slot] = LOG2E * -g00;
    C[2 * M + slot] = LOG2E * c2;
    C[3 * M + slot] = LOG2E * -g11;
    C[4 * M + slot] = LOG2E * c4;
    C[5 * M + slot] = LOG2E * -g01s;
    myuni &= (g00 == rg00) & (g01 == rg01) & (g11 == rg11);
  }
  uni[t] = myuni; __syncthreads();
  for (int s = 128; s > 0; s >>= 1) {
    if (t < s) uni[t] &= uni[t + s];
    __syncthreads();
  }

  // per-chunk bbox + max wlog meta
  float* Mcx = C + 6 * M + 16;
  float* Mcy = Mcx + NC;
  float* Mrx = Mcy + NC;
  float* Mry = Mrx + NC;
  float* Mw  = Mry + NC;
  for (int c = t; c < NC; c += 256) {
    if (psort) {
      float mn0 = INFINITY, mx0 = -INFINITY, mn1 = INFINITY, mx1 = -INFINITY;
      float wl = -INFINITY;
      for (int k = 0; k < CH; ++k) {
        const float u0 = sMu0[c * CH + k], u1 = sMu1[c * CH + k];
        mn0 = fminf(mn0, u0); mx0 = fmaxf(mx0, u0);
        mn1 = fminf(mn1, u1); mx1 = fmaxf(mx1, u1);
        wl = fmaxf(wl, sWl[c * CH + k]);
      }
      Mcx[c] = 0.5f * (mn0 + mx0); Mrx[c] = 0.5f * (mx0 - mn0);
      Mcy[c] = 0.5f * (mn1 + mx1); Mry[c] = 0.5f * (mx1 - mn1);
      Mw[c] = wl;
    } else {
      Mcx[c] = 0.f; Mcy[c] = 0.f; Mrx[c] = 1e30f; Mry[c] = 1e30f; Mw[c] = 1e30f;
    }
  }

  if (t == 0) {
    ((int*)C)[6 * M + 0] = uni[0];
    C[6 * M + 1] = LOG2E * -rg00;        // cb1
    C[6 * M + 2] = LOG2E * -rg11;        // cb3
    C[6 * M + 3] = LOG2E * -2.0f * rg01; // cb5
    float tr = rg00 + rg11;
    float d0 = rg00 - rg11;
    float disc = sqrtf(d0 * d0 + 4.f * rg01 * rg01);
    float lam = 0.5f * (tr - disc);
    if (!(lam > 0.f)) lam = 0.f;
    C[6 * M + 4] = LOG2E * lam;          // lamL: L*lambda_min(G)
  }
}

// ---- sample counting sort (64x64 cells over [-2,2]^2) ----
static __device__ __forceinline__ int scell(float x, float y) {
  int cx = (int)((x + 2.0f) * 16.0f); cx = min(SC - 1, max(0, cx));
  int cy = (int)((y + 2.0f) * 16.0f); cy = min(SC - 1, max(0, cy));
  return cy * SC + cx;
}

__global__ __launch_bounds__(256) void s_hist(
    const float2* __restrict__ sp, int* __restrict__ hist, int N) {
  int i = blockIdx.x * blockDim.x + threadIdx.x;
  const int stride = gridDim.x * blockDim.x;
  for (; i < N; i += stride) {
    const float2 p = sp[i];
    atomicAdd(&hist[scell(p.x, p.y)], 1);
  }
}

__global__ __launch_bounds__(256) void s_scan(int* __restrict__ hist) {
  __shared__ int part[256];
  const int t = threadIdx.x;
  int v[16]; int sum = 0;
#pragma unroll
  for (int k = 0; k < 16; ++k) { v[k] = hist[t * 16 + k]; sum += v[k]; }
  part[t] = sum; __syncthreads();
  if (t == 0) {
    int acc = 0;
    for (int i = 0; i < 256; ++i) { int x = part[i]; part[i] = acc; acc += x; }
  }
  __syncthreads();
  int acc = part[t];
#pragma unroll
  for (int k = 0; k < 16; ++k) { int x = v[k]; hist[t * 16 + k] = acc; acc += x; }
}

__global__ __launch_bounds__(256) void s_scatter(
    const float2* __restrict__ sp, int* __restrict__ offs,
    float2* __restrict__ ss, int* __restrict__ perm, int N) {
  int i = blockIdx.x * blockDim.x + threadIdx.x;
  const int stride = gridDim.x * blockDim.x;
  for (; i < N; i += stride) {
    const float2 p = sp[i];
    const int slot = atomicAdd(&offs[scell(p.x, p.y)], 1);
    ss[slot] = p;
    perm[slot] = i;
  }
}

// process one chunk of CH comps at plane offset MG (uses x0q,x1q,mx,s,tminv)
#define PROCESS(MG) do {                                                     \
    v4f a_[CH];                                                              \
    _Pragma("unroll")                                                        \
    for (int j = 0; j < CH; ++j) {                                           \
      const float c0_ = Cp0[(MG) + j], c2_ = Cp2[(MG) + j],                  \
                  c4_ = Cp4[(MG) + j];                                       \
      v4f t_ = x0q * c2_ + c0_;                                              \
      a_[j] = x1q * c4_ + t_;                                                \
    }                                                                        \
    v4f t0_ = V4MAX(a_[0], a_[1]);                                           \
    v4f t1_ = V4MAX(a_[2], a_[3]);                                           \
    v4f t2_ = V4MAX(a_[4], a_[5]);                                           \
    v4f t3_ = V4MAX(a_[6], a_[7]);                                           \
    _Pragma("unroll")                                                        \
    for (int j = 8; j < CH; j += 4) {                                        \
      t0_ = V4MAX(t0_, a_[j]);     t1_ = V4MAX(t1_, a_[j + 1]);              \
      t2_ = V4MAX(t2_, a_[j + 2]); t3_ = V4MAX(t3_, a_[j + 3]);              \
    }                                                                        \
    const v4f cm_ = V4MAX(V4MAX(t0_, t1_), V4MAX(t2_, t3_));                 \
    const v4f nm_ = V4MAX(mx, cm_);                                          \
    const v4f resc_ = exp2_hw4(mx - nm_);                                    \
    const v4f knm_ = SCH_K2 - nm_ * SCH_K1;                                  \
    v4f l0_ = {0.f, 0.f, 0.f, 0.f}, l1_ = {0.f, 0.f, 0.f, 0.f};              \
    _Pragma("unroll")                                                        \
    for (int j = 0; j < CH; j += 2) {                                        \
      v4f u0_ = a_[j] * SCH_K1 + knm_;                                       \
      v4f u1_ = a_[j + 1] * SCH_K1 + knm_;                                   \
      u0_ = V4MAX(u0_, tminv);                                               \
      u1_ = V4MAX(u1_, tminv);                                               \
      const i4 iv0_ = __builtin_convertvector(u0_, i4);                      \
      const i4 iv1_ = __builtin_convertvector(u1_, i4);                      \
      l0_ += __builtin_bit_cast(v4f, iv0_);                                  \
      l1_ += __builtin_bit_cast(v4f, iv1_);                                  \
    }                                                                        \
    s = s * resc_ + (l0_ + l1_);                                             \
    mx = nm_;                                                                \
  } while (0)

// anchor = wave-min over lanes & 4 samples of achieved full-space max
#define ANCHOR(dst) do {                                                     \
    v4f t_ = mx + base4;                                                     \
    float am_ = fminf(fminf(t_.x, t_.y), fminf(t_.z, t_.w));                 \
    _Pragma("unroll")                                                        \
    for (int o_ = 32; o_; o_ >>= 1)                                          \
      am_ = fminf(am_, __shfl_xor(am_, o_, 64));                             \
    dst = am_;                                                               \
  } while (0)

#define CHUNK_UB(G, UBV) do {                                                \
    const float ccx_ = Mcx[G], ccy_ = Mcy[G];                                \
    const float crx_ = Mrx[G], cry_ = Mry[G], mwv_ = Mw[G];                  \
    const float dx_ = fmaxf(0.f, fabsf(wcx - ccx_) - (wrx + crx_));          \
    const float dy_ = fmaxf(0.f, fabsf(wcy - ccy_) - (wry + cry_));          \
    UBV = mwv_ - lamL * (dx_ * dx_ + dy_ * dy_);                             \
  } while (0)

// One block = 512 threads = 8 waves; all waves share the SAME 256 samples
// (lane l -> slots blk*256 + l + {0,64,128,192}); fast path: wave v owns
// chunks {v, v+8, v+16, ...} (round-robin over sorted chunks).
__global__ __launch_bounds__(512, 4) void gmix_kernel(
    const float2* __restrict__ xs,     // sorted (or raw) samples
    const int* __restrict__ perm,      // slot -> original index (or null)
    const float* __restrict__ C,
    float* __restrict__ out,
    int N, int M, int blkmask) {       // blkmask = nblocks-1 if pow2 else 0
  __shared__ float Lmx[SPLIT][4][64];
  __shared__ float Lsm[SPLIT][4][64];

  const int lane = threadIdx.x & 63;
  const int wave = __builtin_amdgcn_readfirstlane((int)(threadIdx.x >> 6));
  int blk = blockIdx.x;
  if (blkmask) blk = (blk * 97) & blkmask;   // spread heavy (central) blocks
  const int n0 = blk * 256 + lane;

  const float2 z2 = make_float2(0.f, 0.f);
  const float2 xs0 = (n0       < N) ? xs[n0      ] : z2;
  const float2 xs1 = (n0 + 64  < N) ? xs[n0 + 64 ] : z2;
  const float2 xs2 = (n0 + 128 < N) ? xs[n0 + 128] : z2;
  const float2 xs3 = (n0 + 192 < N) ? xs[n0 + 192] : z2;
  const v4f x0q = {xs0.x, xs1.x, xs2.x, xs3.x};
  const v4f x1q = {xs0.y, xs1.y, xs2.y, xs3.y};

  const int flag = ((const int*)C)[6 * M + 0];
  const float cb1 = C[6 * M + 1];
  const float cb3 = C[6 * M + 2];
  const float cb5 = C[6 * M + 3];

  const int Mq = M / SPLIT;
  v4f base4 = {0.f, 0.f, 0.f, 0.f};
  v4f mx = {-INFINITY, -INFINITY, -INFINITY, -INFINITY};
  v4f s  = {0.f, 0.f, 0.f, 0.f};
  const v4f tminv = {SCH_TMIN, SCH_TMIN, SCH_TMIN, SCH_TMIN};

  if (flag) {
    base4 = cb1 * x0q * x0q + cb3 * x1q * x1q + cb5 * x0q * x1q;

    // wave bbox over its 256 samples (identical across the block's waves)
    float b0n = fminf(fminf(x0q.x, x0q.y), fminf(x0q.z, x0q.w));
    float b0x = fmaxf(fmaxf(x0q.x, x0q.y), fmaxf(x0q.z, x0q.w));
    float b1n = fminf(fminf(x1q.x, x1q.y), fminf(x1q.z, x1q.w));
    float b1x = fmaxf(fmaxf(x1q.x, x1q.y), fmaxf(x1q.z, x1q.w));
#pragma unroll
    for (int o = 32; o; o >>= 1) {
      b0n = fminf(b0n, __shfl_xor(b0n, o, 64));
      b0x = fmaxf(b0x, __shfl_xor(b0x, o, 64));
      b1n = fminf(b1n, __shfl_xor(b1n, o, 64));
      b1x = fmaxf(b1x, __shfl_xor(b1x, o, 64));
    }
    const float wcx = 0.5f * (b0n + b0x), wrx = 0.5f * (b0x - b0n);
    const float wcy = 0.5f * (b1n + b1x), wry = 0.5f * (b1x - b1n);

    const int NC = M / CH;
    const int CPW = Mq / CH;               // chunks per wave
    const float lamL = C[6 * M + 4];
    const float* __restrict__ Mcx = C + 6 * M + 16;
    const float* __restrict__ Mcy = Mcx + NC;
    const float* __restrict__ Mrx = Mcy + NC;
    const float* __restrict__ Mry = Mrx + NC;
    const float* __restrict__ Mw  = Mry + NC;
    const float* __restrict__ Cp0 = C;
    const float* __restrict__ Cp2 = C + 2 * M;
    const float* __restrict__ Cp4 = C + 4 * M;

    // pass 1: pick anchor chunk (max UB) and process it
    float best = -INFINITY; int bestc = 0;
#pragma unroll 1
    for (int c = 0; c < CPW; ++c) {
      const int g = wave + SPLIT * c;
      float ub; CHUNK_UB(g, ub);
      if (ub > best) { best = ub; bestc = c; }
    }
    const int bc = __builtin_amdgcn_readfirstlane(bestc);
    {
      const int mg = (wave + SPLIT * bc) * CH;
      PROCESS(mg);
    }
    float anc; ANCHOR(anc);

    // pass 2: remaining chunks with conservative skip
#pragma unroll 1
    for (int c = 0; c < CPW; ++c) {
      if (c == bc) continue;
      const int g = wave + SPLIT * c;
      float ub; CHUNK_UB(g, ub);
      if (ub < anc - T_SKIP) continue;     // contribution < 2^-21 relative
      const int mg = g * CH;
      PROCESS(mg);
      ANCHOR(anc);
    }
  } else {
    // general path: contiguous range per wave, no skip (exact as R9b)
    const int m0 = wave * Mq;
    const float* __restrict__ C0 = C + m0;
    const float* __restrict__ C1 = C + M + m0;
    const float* __restrict__ C2 = C + 2 * M + m0;
    const float* __restrict__ C3 = C + 3 * M + m0;
    const float* __restrict__ C4 = C + 4 * M + m0;
    const float* __restrict__ C5 = C + 5 * M + m0;
    for (int m = 0; m < Mq; m += CHG) {
      v4f a[CHG];
#pragma unroll
      for (int j = 0; j < CHG; ++j) {
        const float c0 = C0[m + j], c1 = C1[m + j], c2 = C2[m + j];
        const float c3 = C3[m + j], c4 = C4[m + j], c5 = C5[m + j];
        v4f u = x0q * c1 + c2;
        u = x1q * c5 + u;
        v4f v = x1q * c3 + c4;
        v4f r = u * x0q + c0;
        a[j] = v * x1q + r;
      }
      v4f t0 = V4MAX(a[0], a[1]);
      v4f t1 = V4MAX(a[2], a[3]);
      v4f t2 = V4MAX(a[4], a[5]);
      v4f t3 = V4MAX(a[6], a[7]);
      const v4f cm = V4MAX(V4MAX(t0, t1), V4MAX(t2, t3));
      const v4f nm = V4MAX(mx, cm);
      const v4f resc = exp2_hw4(mx - nm);
      v4f l0 = {0.f, 0.f, 0.f, 0.f}, l1 = {0.f, 0.f, 0.f, 0.f};
#pragma unroll
      for (int j = 0; j < CHG; j += 2) {
        l0 += exp2_hw4(a[j] - nm);
        l1 += exp2_hw4(a[j + 1] - nm);
      }
      s = s * resc + (l0 + l1);
      mx = nm;
    }
  }

  // fold per-sample base into the partial max; combine waves via LDS
#pragma unroll
  for (int k = 0; k < 4; ++k) {
    Lmx[wave][k][lane] = mx[k] + base4[k];
    Lsm[wave][k][lane] = s[k];
  }
  __syncthreads();

  if (wave < 4) {
    const int set = wave;
    const int slot = blk * 256 + set * 64 + lane;
    if (slot < N) {
      float gm = Lmx[0][set][lane];
#pragma unroll
      for (int v = 1; v < SPLIT; ++v) gm = fmaxf(gm, Lmx[v][set][lane]);
      float S = 0.f;
#pragma unroll
      for (int v = 0; v < SPLIT; ++v)
        S += Lsm[v][set][lane] * EXP2(Lmx[v][set][lane] - gm);
      const int outn = perm ? perm[slot] : slot;
      out[outn] = (gm + __log2f(S)) * 0.69314718055994530942f;
    }
  }
}

extern "C" void kernel_launch(void* const* d_in, const int* in_sizes, int n_in,
                              void* d_out, int out_size, void* d_ws, size_t ws_size,
                              hipStream_t stream) {
  const float* sample = (const float*)d_in[0];
  const float* mu     = (const float*)d_in[1];
  const float* A      = (const float*)d_in[2];
  const float* w      = (const float*)d_in[3];
  float* out = (float*)d_out;

  const int N = in_sizes[0] / 2;   // sample is (N,2)
  const int M = in_sizes[3];       // w is (M,1)

  float* C = (float*)d_ws;
  const int NC = M / CH;
  const size_t cBytes = ((size_t)6 * M + 16 + 5 * (size_t)NC) * 4;
  const size_t offHist = (cBytes + 255) & ~(size_t)255;
  const size_t offSS   = (offHist + (size_t)SCELLS * 4 + 255) & ~(size_t)255;
  const size_t offPerm = (offSS + (size_t)N * 8 + 255) & ~(size_t)255;
  const size_t need    = offPerm + (size_t)N * 4;

  const bool sortEn = (ws_size >= need) && (M % (SPLIT * CH) == 0) &&
                      (M <= MAXM_SORT) && (N >= 256);
  const int nblocks = (N + 255) / 256;
  const int blkmask = (sortEn && ((nblocks & (nblocks - 1)) == 0))
                          ? (nblocks - 1) : 0;

  prep_kernel<<<1, 256, 0, stream>>>(mu, A, w, C, M, sortEn ? 1 : 0);

  if (sortEn) {
    int* hist    = (int*)((char*)d_ws + offHist);
    float2* ss   = (float2*)((char*)d_ws + offSS);
    int* permArr = (int*)((char*)d_ws + offPerm);
    hipMemsetAsync(hist, 0, (size_t)SCELLS * 4, stream);
    s_hist<<<256, 256, 0, stream>>>((const float2*)sample, hist, N);
    s_scan<<<1, 256, 0, stream>>>(hist);
    s_scatter<<<256, 256, 0, stream>>>((const float2*)sample, hist, ss, permArr, N);
    gmix_kernel<<<nblocks, 512, 0, stream>>>(ss, permArr, C, out, N, M, blkmask);
  } else {
    gmix_kernel<<<nblocks, 512, 0, stream>>>((const float2*)sample, nullptr,
                                             C, out, N, M, 0);
  }
}